// Round 5
// baseline (163.542 us; speedup 1.0000x reference)
//
#include <hip/hip_runtime.h>
#include <hip/hip_bf16.h>

constexpr int E     = 2048;   // edges
constexpr int NVARS = 512;    // variable nodes
constexpr int MAXP  = 24;     // table slots per column (max fan-in ~14)
constexpr int NBLK  = MAXP / 4;           // 6 four-entry blocks per column
constexpr int NCH   = 32;     // row chunks for deterministic compaction
constexpr int CHR   = E / NCH;            // 64 rows per chunk
constexpr int CAP   = 12;     // staged entries per (chunk, column); P(overflow) ~ 0
constexpr int TB    = 8;      // batch rows per block in main kernel
constexpr int NT    = 512;    // threads per block in main kernel

// RNE float -> bf16 (kept in HIGH 16 bits).
__device__ __forceinline__ unsigned bf16hi(float f) {
    const unsigned uu = __float_as_uint(f);
    return (uu + 0x7FFFu + ((uu >> 16) & 1u)) & 0xFFFF0000u;
}
// pack two floats as bf16 pair: a -> low half, b -> high half
__device__ __forceinline__ unsigned pk2(float a, float b) {
    return (bf16hi(a) >> 16) | bf16hi(b);
}
__device__ __forceinline__ float bl(unsigned q) { return __uint_as_float(q << 16); }
__device__ __forceinline__ float bh(unsigned q) { return __uint_as_float(q & 0xFFFF0000u); }

// ---------------------------------------------------------------------------
// K1: one coalesced pass over the ExE mask. Stages row indices (u16) per
// (64-row chunk, column) + u8 counts. Also scans this chunk's 16-row stripe
// of the skip mask (exactly one nonzero per column overall -> single writer).
// grid (E/256, NCH) = (8, 32), 256 threads.
// ---------------------------------------------------------------------------
__global__ __launch_bounds__(256)
void k_stage(const float* __restrict__ mask,
             const float* __restrict__ skip_mask,
             const float* __restrict__ llr_w,
             unsigned short* __restrict__ stage,
             unsigned char*  __restrict__ ccnt,
             float*          __restrict__ skw,
             unsigned short* __restrict__ vsrc)
{
    const int col = blockIdx.x * 256 + threadIdx.x;
    const int ch  = blockIdx.y;
    const int r0  = ch * CHR;

    int cnt = 0;
    for (int r = r0; r < r0 + CHR; ++r) {
        if (mask[(size_t)r * E + col] != 0.0f) {
            if (cnt < CAP)
                stage[(size_t)(ch * CAP + cnt) * E + col] = (unsigned short)r;
            ++cnt;
        }
    }
    ccnt[ch * E + col] = (unsigned char)((cnt < CAP) ? cnt : CAP);

    const int v0 = ch * (NVARS / NCH);            // 16-row stripe
    for (int v = v0; v < v0 + NVARS / NCH; ++v) {
        const float m = skip_mask[(size_t)v * E + col];
        if (m != 0.0f) {
            skw [col] = m * llr_w[(size_t)v * E + col];
            vsrc[col] = (unsigned short)v;
        }
    }
}

// ---------------------------------------------------------------------------
// K2: per-column merge. Prefix over chunk counts (row order preserved ->
// deterministic), gather odd_w at nonzeros, apply dropout gate, write packed
// slot-block-major table (uint4 block = 4 slots of one column, coalesced
// across columns), explicit zero padding + zero guard block. Emits meta.
// grid (E/64) = 32 blocks, 64 threads.
// ---------------------------------------------------------------------------
__global__ __launch_bounds__(64)
void k_build(const unsigned short* __restrict__ stage,
             const unsigned char*  __restrict__ ccnt,
             const float* __restrict__ odd_w,
             const float* __restrict__ u,
             const float* __restrict__ logits,
             const float* __restrict__ skw,
             const unsigned short* __restrict__ vsrc,
             unsigned int* __restrict__ tbl,
             float2*       __restrict__ meta)
{
    const int col = blockIdx.x * 64 + threadIdx.x;

    int base = 0;
    for (int ch = 0; ch < NCH; ++ch) {
        const int c = ccnt[ch * E + col];
        for (int j = 0; j < c; ++j) {
            if (base < MAXP) {
                const int r   = stage[(size_t)(ch * CAP + j) * E + col];
                const float sig = 1.0f / (1.0f + __expf(-logits[r]));
                const float z   = (u[r] < sig) ? 1.0f : 0.0f;
                const float w   = odd_w[(size_t)r * E + col] * z;   // mask == 1.0
                tbl[((size_t)(base >> 2) * E + col) * 4 + (base & 3)] =
                    bf16hi(w) | (unsigned)r;
            }
            ++base;
        }
    }
    const int tot = (base < MAXP) ? base : MAXP;
    const int nb  = (tot + 3) >> 2;
    for (int s = tot; s < nb * 4; ++s)                    // pad partial block
        tbl[((size_t)(s >> 2) * E + col) * 4 + (s & 3)] = 0u;
    #pragma unroll
    for (int q = 0; q < 4; ++q)                           // guard block
        tbl[((size_t)nb * E + col) * 4 + q] = 0u;

    meta[col] = make_float2(skw[col],
                            __int_as_float((int)vsrc[col] | (nb << 16)));
}

// tanh(0.5*clip(s,-10,10)) = (e^c - 1)/(e^c + 1)
__device__ __forceinline__ float tanh_half_clip(float s) {
    float c = fminf(fmaxf(s, -10.0f), 10.0f);
    float t = __expf(c);
    return (t - 1.0f) * __frcp_rn(t + 1.0f);
}

// ---------------------------------------------------------------------------
// Main fused kernel. TB=8 batch rows; x AND llr staged in LDS as bf16 packed
// 8-rows-per-uint4 => ONE ds_read_b128 serves all 8 rows of a gather entry.
// Table read as coalesced uint4 (4 entries) with register prefetch.
// LDS = 32 KB (xs) + 8 KB (ls) = 40 KB -> 4 blocks/CU, 32 waves/CU.
// ---------------------------------------------------------------------------
__global__ __launch_bounds__(NT, 8)
void fused_main(const float* __restrict__ x,          // [B, E]
                const float* __restrict__ llr,        // [B, NVARS]
                const unsigned int* __restrict__ tbl, // [NBLK+1][E] uint4 blocks
                const float2* __restrict__ meta,
                float* __restrict__ out)
{
    __shared__ uint4 xs[E];        // 8 bf16 rows per column
    __shared__ uint4 ls[NVARS];    // 8 bf16 rows per variable

    const int b0 = blockIdx.x * TB;
    const int t  = threadIdx.x;

    // Stage x: thread t owns cols 4t..4t+3; 8 coalesced float4 row loads.
    {
        const float4* xr = (const float4*)(x + (size_t)b0 * E);
        const float4 r0 = xr[0 * (E / 4) + t];
        const float4 r1 = xr[1 * (E / 4) + t];
        const float4 r2 = xr[2 * (E / 4) + t];
        const float4 r3 = xr[3 * (E / 4) + t];
        const float4 r4 = xr[4 * (E / 4) + t];
        const float4 r5 = xr[5 * (E / 4) + t];
        const float4 r6 = xr[6 * (E / 4) + t];
        const float4 r7 = xr[7 * (E / 4) + t];
        xs[4 * t + 0] = make_uint4(pk2(r0.x, r1.x), pk2(r2.x, r3.x),
                                   pk2(r4.x, r5.x), pk2(r6.x, r7.x));
        xs[4 * t + 1] = make_uint4(pk2(r0.y, r1.y), pk2(r2.y, r3.y),
                                   pk2(r4.y, r5.y), pk2(r6.y, r7.y));
        xs[4 * t + 2] = make_uint4(pk2(r0.z, r1.z), pk2(r2.z, r3.z),
                                   pk2(r4.z, r5.z), pk2(r6.z, r7.z));
        xs[4 * t + 3] = make_uint4(pk2(r0.w, r1.w), pk2(r2.w, r3.w),
                                   pk2(r4.w, r5.w), pk2(r6.w, r7.w));
    }
    // Stage llr: var v = t (NT == NVARS); 8 coalesced scalar loads.
    {
        const float* lr = llr + (size_t)b0 * NVARS;
        ls[t] = make_uint4(pk2(lr[t],             lr[NVARS + t]),
                           pk2(lr[2 * NVARS + t], lr[3 * NVARS + t]),
                           pk2(lr[4 * NVARS + t], lr[5 * NVARS + t]),
                           pk2(lr[6 * NVARS + t], lr[7 * NVARS + t]));
    }
    __syncthreads();

    #pragma unroll
    for (int k = 0; k < E / NT; ++k) {
        const int e = k * NT + t;
        const float2 mt = meta[e];
        const int vc = __float_as_int(mt.y);
        const int v  = vc & 0xFFFF;
        const int nb = vc >> 16;
        const float sk = mt.x;

        const uint4 lv = ls[v];
        float a0 = sk * bl(lv.x), a1 = sk * bh(lv.x);
        float a2 = sk * bl(lv.y), a3 = sk * bh(lv.y);
        float a4 = sk * bl(lv.z), a5 = sk * bh(lv.z);
        float a6 = sk * bl(lv.w), a7 = sk * bh(lv.w);

        const uint4* tq = (const uint4*)tbl + e;   // [blk][col] blocks
        uint4 g = tq[0];
        for (int ib = 0; ib < nb; ++ib) {
            const uint4 gn = tq[(size_t)(ib + 1) * E];   // guard at blk=nb
            #pragma unroll
            for (int q = 0; q < 4; ++q) {
                const unsigned ent = (q == 0) ? g.x : (q == 1) ? g.y
                                   : (q == 2) ? g.z : g.w;
                const float wv = __uint_as_float(ent & 0xFFFF0000u);
                const int   s  = (int)(ent & 0x7FFu);
                const uint4 xv = xs[s];                  // one ds_read_b128
                a0 += wv * bl(xv.x); a1 += wv * bh(xv.x);
                a2 += wv * bl(xv.y); a3 += wv * bh(xv.y);
                a4 += wv * bl(xv.z); a5 += wv * bh(xv.z);
                a6 += wv * bl(xv.w); a7 += wv * bh(xv.w);
            }
            g = gn;
        }

        const size_t o = (size_t)b0 * E + e;
        out[o]         = tanh_half_clip(a0);
        out[o + E]     = tanh_half_clip(a1);
        out[o + 2 * E] = tanh_half_clip(a2);
        out[o + 3 * E] = tanh_half_clip(a3);
        out[o + 4 * E] = tanh_half_clip(a4);
        out[o + 5 * E] = tanh_half_clip(a5);
        out[o + 6 * E] = tanh_half_clip(a6);
        out[o + 7 * E] = tanh_half_clip(a7);
    }
}

extern "C" void kernel_launch(void* const* d_in, const int* in_sizes, int n_in,
                              void* d_out, int out_size, void* d_ws, size_t ws_size,
                              hipStream_t stream) {
    const float* x        = (const float*)d_in[0];  // [B, E]
    const float* llr      = (const float*)d_in[1];  // [B, NVARS]
    const float* u        = (const float*)d_in[2];  // [E]
    const float* odd_w    = (const float*)d_in[3];  // [E, E]
    const float* llr_w    = (const float*)d_in[4];  // [NVARS, E]
    const float* logits   = (const float*)d_in[5];  // [E]
    const float* o2e_mask = (const float*)d_in[6];  // [E, E]
    const float* skip_msk = (const float*)d_in[7];  // [NVARS, E]
    float* out = (float*)d_out;

    const int B = in_sizes[0] / E;                  // 16384

    // Workspace layout (~1.9 MB), 16B-aligned chunks first.
    char* wsb = (char*)d_ws;
    size_t off = 0;
    unsigned int*   tbl   = (unsigned int*)(wsb + off);  off += (size_t)(NBLK + 1) * E * 16; // 229376
    float2*         meta  = (float2*)(wsb + off);        off += (size_t)E * 8;               //  16384
    float*          skw   = (float*)(wsb + off);         off += (size_t)E * 4;               //   8192
    unsigned short* stage = (unsigned short*)(wsb + off);off += (size_t)NCH * CAP * E * 2;   // 1572864
    unsigned short* vsrc  = (unsigned short*)(wsb + off);off += (size_t)E * 2;               //   4096
    unsigned char*  ccnt  = (unsigned char*)(wsb + off); off += (size_t)NCH * E;             //  65536

    k_stage<<<dim3(E / 256, NCH), dim3(256), 0, stream>>>(
        o2e_mask, skip_msk, llr_w, stage, ccnt, skw, vsrc);
    k_build<<<dim3(E / 64), dim3(64), 0, stream>>>(
        stage, ccnt, odd_w, u, logits, skw, vsrc, tbl, meta);

    fused_main<<<dim3(B / TB), dim3(NT), 0, stream>>>(x, llr, tbl, meta, out);
}